// Round 2
// baseline (304.192 us; speedup 1.0000x reference)
//
#include <hip/hip_runtime.h>

// Problem constants
#define BB 262144   // batch rows
// d_out layout: action [B,6] @0, latent_vf [B,128] @6B, expout [B,12] @134B

typedef float fx4 __attribute__((ext_vector_type(4)));
typedef float fx2 __attribute__((ext_vector_type(2)));
typedef short sx8 __attribute__((ext_vector_type(8)));   // 8 bf16 in 4 VGPRs

// Packed bf16 B-fragment weight table lives in module-owned device memory:
// d_ws proved unsafe (round 1: ws overrun corrupted the harness's pristine
// input copies -> deterministic post-timing divergence on latent_vf).
// Layout (element offsets):
//   W0f  [128x128] KT=4 NT=8  @ 0      (16384)
//   W1f  [128x64]  KT=4 NT=4  @ 16384  (8192)
//   Wvf  [64x128]  KT=2 NT=8  @ 24576  (8192)
//   We1f [64x128]  KT=2 NT=8  @ 32768  (8192)
//   W2f  [128x16]  KT=4 NT=1  @ 40960  (2048)
//   Wgf  [64x16]   KT=2 NT=1  @ 43008  (1024)
__device__ unsigned short g_Wf[44032];

__device__ __forceinline__ unsigned short f2bf(float f) {
    unsigned u = __builtin_bit_cast(unsigned, f);
    u += 0x7fffu + ((u >> 16) & 1u);   // RNE
    return (unsigned short)(u >> 16);
}

__device__ __forceinline__ sx8 cvt8(fx4 a, fx4 b) {
    sx8 r;
    r[0] = (short)f2bf(a[0]); r[1] = (short)f2bf(a[1]);
    r[2] = (short)f2bf(a[2]); r[3] = (short)f2bf(a[3]);
    r[4] = (short)f2bf(b[0]); r[5] = (short)f2bf(b[1]);
    r[6] = (short)f2bf(b[2]); r[7] = (short)f2bf(b[3]);
    return r;
}

__device__ __forceinline__ float fast_tanh(float x) {
    x = fminf(15.f, fmaxf(-15.f, x));
    float t = __builtin_amdgcn_exp2f(x * 2.8853900817779268f); // e^(2x)
    return (t - 1.f) * __builtin_amdgcn_rcpf(t + 1.f);
}

__device__ __forceinline__ float fast_softplus(float x) {
    float xc = fminf(30.f, fmaxf(-30.f, x));
    float e = __builtin_amdgcn_exp2f(xc * 1.4426950408889634f);
    return 0.6931471805599453f * __builtin_amdgcn_logf(1.f + e);
}

// ---------------------------------------------------------------------------
// Unified weight packer: fp32 -> bf16 MFMA B-fragment layout into g_Wf.
// Fragment layout: frag block (nt*KT + kt); within block lane-major, 8 bf16/lane.
// Lane l holds B[k = kt*32 + (l>>4)*8 + j][n = nt*16 + (l&15)], j=0..7.
// ---------------------------------------------------------------------------
__global__ void pack_all(const float* __restrict__ Ws0, const float* __restrict__ Ws1,
                         const float* __restrict__ Wv,  const float* __restrict__ wg,
                         const float* __restrict__ wn,  const float* __restrict__ We1,
                         const float* __restrict__ We2)
{
    int idx = blockIdx.x * 256 + threadIdx.x;   // grid covers exactly 44032
    int off, KT, mode, Ksrc = 0, Nsrc = 0;
    const float* src; const float* src2 = nullptr;
    if (idx < 16384)      { off = 0;     KT = 4; mode = 0; src = Ws0; Ksrc = 128; Nsrc = 128; }
    else if (idx < 24576) { off = 16384; KT = 4; mode = 0; src = Ws1; Ksrc = 128; Nsrc = 62;  }
    else if (idx < 32768) { off = 24576; KT = 2; mode = 0; src = Wv;  Ksrc = 62;  Nsrc = 128; }
    else if (idx < 40960) { off = 32768; KT = 2; mode = 1; src = We1; }
    else if (idx < 43008) { off = 40960; KT = 4; mode = 2; src = We2; }
    else                  { off = 43008; KT = 2; mode = 3; src = wg; src2 = wn; }

    int rel  = idx - off;
    int blk  = rel >> 9;
    int lane = (rel >> 3) & 63;
    int j    = rel & 7;
    int nt = blk / KT, kt = blk - nt * KT;
    int k = kt * 32 + (lane >> 4) * 8 + j;
    int n = nt * 16 + (lane & 15);
    float v = 0.f;
    if (mode == 0) {
        if (k < Ksrc && n < Nsrc) v = src[k * Nsrc + n];
    } else if (mode == 1) {              // We1[e][k][h] -> W[k][e*64+h]
        if (k < 62) { int e = n >> 6, h = n & 63; v = src[e * 3968 + k * 64 + h]; }
    } else if (mode == 2) {              // We2 block-diag: rows 0-63 -> cols 0-5, rows 64-127 -> cols 6-11
        int e = k >> 6; int c = n - e * 6;
        if ((unsigned)c < 6u) v = src[e * 384 + (k & 63) * 6 + c];
    } else {                             // gating: cols 0,1 = w_gate, 2,3 = w_noise
        if (k < 62) {
            if (n < 2) v = src[k * 2 + n];
            else if (n < 4) v = src2[k * 2 + (n - 2)];
        }
    }
    g_Wf[idx] = f2bf(v);
}

// ---------------------------------------------------------------------------
// Main fused kernel: 128 rows per workgroup, 4 waves, 16x16x32 bf16 MFMA.
// Wave w owns row-tiles m = 2w, 2w+1 (32 rows).
// ---------------------------------------------------------------------------
__global__ __launch_bounds__(256, 2)
void mlp_main(const float* __restrict__ X, const float* __restrict__ noise,
              const float* __restrict__ bs0, const float* __restrict__ bs1,
              const float* __restrict__ bv,  const float* __restrict__ be1,
              const float* __restrict__ be2, float* __restrict__ out)
{
    __shared__ __align__(16) unsigned short sH[128 * 136];  // 34816 B (H, then eh overlay)
    __shared__ __align__(16) unsigned short sL[128 * 72];   // 18432 B (latent)
    __shared__ __align__(16) float sS[128 * 21];            // 10752 B (cols 0-15 expert logits, 16-19 gating)

    const int tid  = threadIdx.x;
    const int wave = tid >> 6;
    const int lane = tid & 63;
    const int lr   = lane & 15;   // A row / B col / C col
    const int lq   = lane >> 4;   // quad
    const int r0   = blockIdx.x * 128;

    const unsigned short* W0f  = g_Wf;
    const unsigned short* W1f  = g_Wf + 16384;
    const unsigned short* Wvf  = g_Wf + 24576;
    const unsigned short* We1f = g_Wf + 32768;
    const unsigned short* W2f  = g_Wf + 40960;
    const unsigned short* Wgf  = g_Wf + 43008;

    float* out_act = out;                       // [B,6]
    float* out_vf  = out + (size_t)6 * BB;      // [B,128]
    float* out_eo  = out + (size_t)134 * BB;    // [B,12]

    // ---- Stage 1: H = tanh(X @ W0 + b0), A-frags straight from global fp32
    sx8 a[2][4];
    for (int m = 0; m < 2; m++) {
        const float* p = X + (size_t)(r0 + (wave * 2 + m) * 16 + lr) * 128 + lq * 8;
        for (int kt = 0; kt < 4; kt++) {
            fx4 u = *(const fx4*)(p + kt * 32);
            fx4 v = *(const fx4*)(p + kt * 32 + 4);
            a[m][kt] = cvt8(u, v);
        }
    }
    for (int nt = 0; nt < 8; nt++) {
        sx8 b[4];
        for (int kt = 0; kt < 4; kt++)
            b[kt] = *(const sx8*)(W0f + (((nt * 4 + kt) * 64 + lane) << 3));
        int col = nt * 16 + lr;
        float bias = bs0[col];
        for (int m = 0; m < 2; m++) {
            fx4 acc = {0.f, 0.f, 0.f, 0.f};
            for (int kt = 0; kt < 4; kt++)
                acc = __builtin_amdgcn_mfma_f32_16x16x32_bf16(a[m][kt], b[kt], acc, 0, 0, 0);
            unsigned short* dst = sH + ((wave * 2 + m) * 16 + lq * 4) * 136 + col;
            for (int r = 0; r < 4; r++)
                dst[r * 136] = f2bf(fast_tanh(acc[r] + bias));
        }
    }
    __syncthreads();

    // ---- Stage 2: L = tanh(H @ W1 + b1), cols 62,63 are zero-pad
    for (int m = 0; m < 2; m++)
        for (int kt = 0; kt < 4; kt++)
            a[m][kt] = *(const sx8*)(sH + ((wave * 2 + m) * 16 + lr) * 136 + kt * 32 + lq * 8);
    for (int nt = 0; nt < 4; nt++) {
        sx8 b[4];
        for (int kt = 0; kt < 4; kt++)
            b[kt] = *(const sx8*)(W1f + (((nt * 4 + kt) * 64 + lane) << 3));
        int col = nt * 16 + lr;
        float bias = (col < 62) ? bs1[col] : 0.f;
        for (int m = 0; m < 2; m++) {
            fx4 acc = {0.f, 0.f, 0.f, 0.f};
            for (int kt = 0; kt < 4; kt++)
                acc = __builtin_amdgcn_mfma_f32_16x16x32_bf16(a[m][kt], b[kt], acc, 0, 0, 0);
            unsigned short* dst = sL + ((wave * 2 + m) * 16 + lq * 4) * 72 + col;
            for (int r = 0; r < 4; r++)
                dst[r * 72] = f2bf(fast_tanh(acc[r] + bias));
        }
    }
    __syncthreads();

    // ---- Stage 3a: eh = relu(L @ We1c + be1c) -> sH (overlay, H is dead)
    sx8 aL[2][2];
    for (int m = 0; m < 2; m++)
        for (int kt = 0; kt < 2; kt++)
            aL[m][kt] = *(const sx8*)(sL + ((wave * 2 + m) * 16 + lr) * 72 + kt * 32 + lq * 8);
    for (int nt = 0; nt < 8; nt++) {
        sx8 b0 = *(const sx8*)(We1f + (((nt * 2 + 0) * 64 + lane) << 3));
        sx8 b1 = *(const sx8*)(We1f + (((nt * 2 + 1) * 64 + lane) << 3));
        int col = nt * 16 + lr;
        float bias = be1[col];   // be1 flat [2,64] == combined [128]
        for (int m = 0; m < 2; m++) {
            fx4 acc = {0.f, 0.f, 0.f, 0.f};
            acc = __builtin_amdgcn_mfma_f32_16x16x32_bf16(aL[m][0], b0, acc, 0, 0, 0);
            acc = __builtin_amdgcn_mfma_f32_16x16x32_bf16(aL[m][1], b1, acc, 0, 0, 0);
            unsigned short* dst = sH + ((wave * 2 + m) * 16 + lq * 4) * 136 + col;
            for (int r = 0; r < 4; r++)
                dst[r * 136] = f2bf(fmaxf(acc[r] + bias, 0.f));
        }
    }
    // ---- Stage 3b: latent_vf = tanh(L @ Wv + bv) -> global (output 1)
    for (int nt = 0; nt < 8; nt++) {
        sx8 b0 = *(const sx8*)(Wvf + (((nt * 2 + 0) * 64 + lane) << 3));
        sx8 b1 = *(const sx8*)(Wvf + (((nt * 2 + 1) * 64 + lane) << 3));
        int col = nt * 16 + lr;
        float bias = bv[col];
        for (int m = 0; m < 2; m++) {
            fx4 acc = {0.f, 0.f, 0.f, 0.f};
            acc = __builtin_amdgcn_mfma_f32_16x16x32_bf16(aL[m][0], b0, acc, 0, 0, 0);
            acc = __builtin_amdgcn_mfma_f32_16x16x32_bf16(aL[m][1], b1, acc, 0, 0, 0);
            float* dst = out_vf + (size_t)(r0 + (wave * 2 + m) * 16 + lq * 4) * 128 + col;
            for (int r = 0; r < 4; r++)
                dst[(size_t)r * 128] = fast_tanh(acc[r] + bias);
        }
    }
    __syncthreads();

    // ---- Stage 4a: expert-out logits = eh @ W2bd -> sS cols 0..15
    {
        sx8 bw[4];
        for (int kt = 0; kt < 4; kt++)
            bw[kt] = *(const sx8*)(W2f + (((kt) * 64 + lane) << 3));
        for (int m = 0; m < 2; m++) {
            sx8 ae[4];
            for (int kt = 0; kt < 4; kt++)
                ae[kt] = *(const sx8*)(sH + ((wave * 2 + m) * 16 + lr) * 136 + kt * 32 + lq * 8);
            fx4 acc = {0.f, 0.f, 0.f, 0.f};
            for (int kt = 0; kt < 4; kt++)
                acc = __builtin_amdgcn_mfma_f32_16x16x32_bf16(ae[kt], bw[kt], acc, 0, 0, 0);
            float* dst = sS + ((wave * 2 + m) * 16 + lq * 4) * 21 + lr;
            for (int r = 0; r < 4; r++) dst[r * 21] = acc[r];
        }
    }
    // ---- Stage 4b: gating logits = L @ [wg|wn] -> sS cols 16..19
    {
        sx8 bg0 = *(const sx8*)(Wgf + ((0 * 64 + lane) << 3));
        sx8 bg1 = *(const sx8*)(Wgf + ((1 * 64 + lane) << 3));
        for (int m = 0; m < 2; m++) {
            fx4 acc = {0.f, 0.f, 0.f, 0.f};
            acc = __builtin_amdgcn_mfma_f32_16x16x32_bf16(aL[m][0], bg0, acc, 0, 0, 0);
            acc = __builtin_amdgcn_mfma_f32_16x16x32_bf16(aL[m][1], bg1, acc, 0, 0, 0);
            if (lr < 4) {
                float* dst = sS + ((wave * 2 + m) * 16 + lq * 4) * 21 + 16 + lr;
                for (int r = 0; r < 4; r++) dst[r * 21] = acc[r];
            }
        }
    }
    __syncthreads();

    // ---- Epilogue: one thread per row
    if (tid < 128) {
        const float* Srow = sS + tid * 21;
        int grow = r0 + tid;
        fx2 nz = *(const fx2*)(noise + (size_t)grow * 2);
        float sp0 = fast_softplus(Srow[18]) + 1e-2f;
        float sp1 = fast_softplus(Srow[19]) + 1e-2f;
        float l0 = Srow[16] + nz[0] * sp0;
        float l1 = Srow[17] + nz[1] * sp1;
        float mg = fmaxf(l0, l1);
        float e0 = __builtin_amdgcn_exp2f((l0 - mg) * 1.4426950408889634f);
        float e1 = __builtin_amdgcn_exp2f((l1 - mg) * 1.4426950408889634f);
        float gi = __builtin_amdgcn_rcpf(e0 + e1);
        float g0 = e0 * gi, g1 = e1 * gi;

        float eo[12];
        for (int e = 0; e < 2; e++) {
            float lg[6]; float mx = -1e30f;
            for (int c = 0; c < 6; c++) {
                lg[c] = Srow[e * 6 + c] + be2[e * 6 + c];
                mx = fmaxf(mx, lg[c]);
            }
            float s = 0.f;
            for (int c = 0; c < 6; c++) {
                lg[c] = __builtin_amdgcn_exp2f((lg[c] - mx) * 1.4426950408889634f);
                s += lg[c];
            }
            float inv = __builtin_amdgcn_rcpf(s);
            for (int c = 0; c < 6; c++) eo[e * 6 + c] = lg[c] * inv;
        }
        float* pa = out_act + (size_t)grow * 6;
        for (int c = 0; c < 6; c++) pa[c] = g0 * eo[c] + g1 * eo[6 + c];
        float* pe = out_eo + (size_t)grow * 12;
        for (int c = 0; c < 12; c++) pe[c] = eo[c];
    }
}

extern "C" void kernel_launch(void* const* d_in, const int* in_sizes, int n_in,
                              void* d_out, int out_size, void* d_ws, size_t ws_size,
                              hipStream_t stream)
{
    const float* X    = (const float*)d_in[0];
    const float* nz   = (const float*)d_in[1];
    const float* Ws0  = (const float*)d_in[2];
    const float* bs0  = (const float*)d_in[3];
    const float* Ws1  = (const float*)d_in[4];
    const float* bs1  = (const float*)d_in[5];
    const float* Wv   = (const float*)d_in[6];
    const float* bv   = (const float*)d_in[7];
    const float* wg   = (const float*)d_in[8];
    const float* wn   = (const float*)d_in[9];
    const float* We1  = (const float*)d_in[10];
    const float* be1  = (const float*)d_in[11];
    const float* We2  = (const float*)d_in[12];
    const float* be2  = (const float*)d_in[13];

    // Repack weights into module-owned g_Wf every call (same work every call).
    pack_all<<<172, 256, 0, stream>>>(Ws0, Ws1, Wv, wg, wn, We1, We2);

    mlp_main<<<BB / 128, 256, 0, stream>>>(X, nz, bs0, bs1, bv, be1, be2, (float*)d_out);
}